// Round 3
// baseline (108.598 us; speedup 1.0000x reference)
//
#include <hip/hip_runtime.h>
#include <hip/hip_bf16.h>

// Chamfer loss: B=8, P=32, N=M=1024, fp32 in, scalar fp32 out.
// Reference quirk: x[bp,m,c] = rp[bp, (3m+c)%M, (3m+c)>>10]  (torch permute+reshape).
//
// R3: column-split to kill AGPR round-trips seen in R2 (VGPR_Count=60 vs ~115
// live floats). One block per bp, 1024 threads = 16 waves (4/SIMD).
// Wave w: column half h=w&1 (8 cols/lane in registers), row group g=w>>1
// (128 rows). Persistent state/lane = 40 floats -> fits in arch VGPRs.
// Partial row-mins (per half) merged via LDS in epilogue; column mins merged
// 8-way per half. Per-row x precomputed to LDS as (-2x, ||x||^2), broadcast
// ds_read_b128 in hot loop. Scalar out via one atomicAdd per block.

#define MM 1024
#define NN 1024
#define THREADS 1024
#define NWAVES 16
#define HALF 512
#define CPL 8                 // columns per lane (8*64 = 512 = half)
#define RB 4                  // rows per inner batch
#define RPG 128               // rows per group (16 waves / 2 halves = 8 groups)
#define FINF 3.4e38f

__global__ __launch_bounds__(THREADS, 4)
void chamfer_kernel(const float* __restrict__ nrf,   // (BP, N, 3) -> y
                    const float* __restrict__ rp,    // (BP, M, 3) -> x (scrambled view)
                    float* __restrict__ out,
                    float inv_bpm, float inv_bpn) {
    const int bp   = blockIdx.x;
    const int tid  = threadIdx.x;
    const int lane = tid & 63;
    const int wave = tid >> 6;
    const int h    = wave & 1;   // column half
    const int g    = wave >> 1;  // row group

    __shared__ float  rpS[MM * 3];              // 12 KB raw rp block
    __shared__ float4 xS[MM];                   // 16 KB per-row (-2x, ||x||^2)
    __shared__ float  colminS[NWAVES][HALF];    // 32 KB per-wave column-min partials
    __shared__ float  rowminP[NWAVES][RPG];     //  8 KB per-wave partial row mins
    __shared__ float  partialS[NWAVES];

    const float* rpB = rp  + (size_t)bp * MM * 3;
    const float* yB  = nrf + (size_t)bp * NN * 3;

    // Stage rp (coalesced).
    for (int i = tid; i < MM * 3; i += THREADS) rpS[i] = rpB[i];

    // This lane's 8 y-columns (within half h) into registers.
    float y0[CPL], y1[CPL], y2[CPL], yy[CPL], colmin[CPL];
    #pragma unroll
    for (int i = 0; i < CPL; ++i) {
        int n = h * HALF + i * 64 + lane;
        float a = yB[n * 3 + 0];
        float b = yB[n * 3 + 1];
        float c = yB[n * 3 + 2];
        y0[i] = a; y1[i] = b; y2[i] = c;
        yy[i] = a * a + b * b + c * c;
        colmin[i] = FINF;
    }
    __syncthreads();

    // Precompute per-row x params (one row per thread, scrambled view).
    {
        const int k = 3 * tid;
        float a = rpS[((k + 0) & (MM - 1)) * 3 + ((k + 0) >> 10)];
        float b = rpS[((k + 1) & (MM - 1)) * 3 + ((k + 1) >> 10)];
        float c = rpS[((k + 2) & (MM - 1)) * 3 + ((k + 2) >> 10)];
        xS[tid] = make_float4(-2.0f * a, -2.0f * b, -2.0f * c,
                              a * a + b * b + c * c);
    }
    __syncthreads();

    const int m0 = g * RPG;
    for (int r0 = 0; r0 < RPG; r0 += RB) {
        float4 x[RB];
        #pragma unroll
        for (int j = 0; j < RB; ++j) x[j] = xS[m0 + r0 + j];  // broadcast b128

        float rmin[RB];
        #pragma unroll
        for (int j = 0; j < RB; ++j) rmin[j] = FINF;

        #pragma unroll
        for (int i = 0; i < CPL; ++i) {
            const float a = y0[i], b = y1[i], c = y2[i], s = yy[i];
            float e[RB];
            #pragma unroll
            for (int j = 0; j < RB; ++j) {
                e[j] = __builtin_fmaf(x[j].x, a,
                        __builtin_fmaf(x[j].y, b,
                         __builtin_fmaf(x[j].z, c, s)));
                rmin[j] = fminf(rmin[j], e[j]);
            }
            // colmin over d = e + xx; v_min3-friendly chain.
            float d01 = fminf(e[0] + x[0].w, e[1] + x[1].w);
            float d23 = fminf(e[2] + x[2].w, e[3] + x[3].w);
            colmin[i] = fminf(fminf(colmin[i], d01), d23);
        }

        // 4 interleaved 64-lane butterflies (partial mins over this half).
        #pragma unroll
        for (int off = 32; off > 0; off >>= 1) {
            #pragma unroll
            for (int j = 0; j < RB; ++j)
                rmin[j] = fminf(rmin[j], __shfl_xor(rmin[j], off, 64));
        }
        if (lane == 0) {
            *(float4*)&rowminP[wave][r0] =
                make_float4(rmin[0], rmin[1], rmin[2], rmin[3]);
        }
    }

    // Publish per-wave column-min partials.
    #pragma unroll
    for (int i = 0; i < CPL; ++i) colminS[wave][i * 64 + lane] = colmin[i];
    __syncthreads();

    // Epilogue: thread t owns row m=t and column n=t.
    {
        const int m = tid, gg = m >> 7, r = m & (RPG - 1);
        float rmin_full = xS[m].w + fminf(rowminP[2 * gg][r], rowminP[2 * gg + 1][r]);

        const int hh = tid >> 9, c = tid & (HALF - 1);
        float cm = colminS[hh][c];
        #pragma unroll
        for (int w = 1; w < 8; ++w) cm = fminf(cm, colminS[hh + 2 * w][c]);

        float val = rmin_full * inv_bpm + cm * inv_bpn;
        #pragma unroll
        for (int off = 32; off > 0; off >>= 1)
            val += __shfl_xor(val, off, 64);
        if (lane == 0) partialS[wave] = val;
    }
    __syncthreads();

    if (tid == 0) {
        float s = 0.0f;
        #pragma unroll
        for (int w = 0; w < NWAVES; ++w) s += partialS[w];
        atomicAdd(out, s);
    }
}

extern "C" void kernel_launch(void* const* d_in, const int* in_sizes, int n_in,
                              void* d_out, int out_size, void* d_ws, size_t ws_size,
                              hipStream_t stream) {
    const float* nrf = (const float*)d_in[0];  // (B,P,N,3)
    const float* rp  = (const float*)d_in[1];  // (B,P,M,3)
    float* out = (float*)d_out;

    const int BP = in_sizes[1] / (MM * 3);     // 256
    const float inv_bpm = 1.0f / (float)(BP * MM);
    const float inv_bpn = 1.0f / (float)(BP * NN);

    hipMemsetAsync(out, 0, sizeof(float), stream);
    chamfer_kernel<<<BP, THREADS, 0, stream>>>(nrf, rp, out, inv_bpm, inv_bpn);
}

// Round 5
// 97.191 us; speedup vs baseline: 1.1174x; 1.1174x over previous
//
#include <hip/hip_runtime.h>
#include <hip/hip_bf16.h>

// Chamfer loss: B=8, P=32, N=M=1024, fp32 in, scalar fp32 out.
// Reference quirk: x[bp,m,c] = rp[bp, (3m+c)%M, (3m+c)>>10]  (torch permute+reshape).
//
// R4b: R2's shape (wave owns 64 rows x all 1024 cols, RB=4 -> one butterfly
// per row) but y lives in LDS as float4 (y0,y1,y2,||y||^2), read with one
// conflict-free ds_read_b128 per inner iter instead of 64 persistent VGPRs.
// Persistent per-lane state ~56 floats -> fits arch VGPRs (kills the AGPR
// round-trips suspected from VGPR_Count=60 vs ~110 live in R2).
// Row-min reduce: 4x v_min+DPP row_ror(1,2,4,8) (template-const ctrl) +
// ds_swizzle xor16 + ds_bpermute xor32.

#define MM 1024
#define NN 1024
#define THREADS 1024
#define NWAVES 16
#define ROWS_PER_WAVE 64
#define RB 4
#define CPL 16                // col-chunks per lane (16*64 = 1024)
#define FINF 3.4e38f

template <int CTRL>
__device__ __forceinline__ float dpp_ror_min(float v) {
    int vi = __float_as_int(v);
    int t  = __builtin_amdgcn_update_dpp(vi, vi, CTRL, 0xf, 0xf, true);
    return fminf(v, __int_as_float(t));
}

// Full 64-lane min; every lane ends with the result.
__device__ __forceinline__ float wave_min64(float v, int lane_xor32_addr) {
    v = dpp_ror_min<0x121>(v);   // row_ror:1  (16-lane rows)
    v = dpp_ror_min<0x122>(v);   // row_ror:2
    v = dpp_ror_min<0x124>(v);   // row_ror:4
    v = dpp_ror_min<0x128>(v);   // row_ror:8  -> per-16 min
    int s = __builtin_amdgcn_ds_swizzle(__float_as_int(v), 0x401F); // xor 16
    v = fminf(v, __int_as_float(s));
    int p = __builtin_amdgcn_ds_bpermute(lane_xor32_addr, __float_as_int(v));
    return fminf(v, __int_as_float(p));  // xor 32
}

__global__ __launch_bounds__(THREADS, 4)
void chamfer_kernel(const float* __restrict__ nrf,   // (BP, N, 3) -> y
                    const float* __restrict__ rp,    // (BP, M, 3) -> x (scrambled)
                    float* __restrict__ out,
                    float inv_bpm, float inv_bpn) {
    const int bp   = blockIdx.x;
    const int tid  = threadIdx.x;
    const int lane = tid & 63;
    const int wave = tid >> 6;
    const int xaddr32 = ((lane ^ 32) << 2);  // ds_bpermute byte addr

    __shared__ float  rpS[MM * 3];            // 12 KB raw rp block
    __shared__ float4 xS[MM];                 // 16 KB per-row (-2x, ||x||^2)
    __shared__ float4 yS[NN];                 // 16 KB per-col (y, ||y||^2)
    __shared__ float  colminS[NWAVES][NN];    // 64 KB per-wave col-min partials
    __shared__ float  rowsumS[NWAVES];
    __shared__ float  csumS[NWAVES];

    const float* rpB = rp  + (size_t)bp * MM * 3;
    const float* yB  = nrf + (size_t)bp * NN * 3;

    // Phase 0: stage rp raw + build yS (independent).
    for (int i = tid; i < MM * 3; i += THREADS) rpS[i] = rpB[i];
    {
        float a = yB[tid * 3 + 0];
        float b = yB[tid * 3 + 1];
        float c = yB[tid * 3 + 2];
        yS[tid] = make_float4(a, b, c, a * a + b * b + c * c);
    }
    __syncthreads();

    // Phase 1: per-row x params from scrambled view.
    {
        const int k = 3 * tid;
        float a = rpS[((k + 0) & (MM - 1)) * 3 + ((k + 0) >> 10)];
        float b = rpS[((k + 1) & (MM - 1)) * 3 + ((k + 1) >> 10)];
        float c = rpS[((k + 2) & (MM - 1)) * 3 + ((k + 2) >> 10)];
        xS[tid] = make_float4(-2.0f * a, -2.0f * b, -2.0f * c,
                              a * a + b * b + c * c);
    }
    __syncthreads();

    float colmin[CPL];
    #pragma unroll
    for (int i = 0; i < CPL; ++i) colmin[i] = FINF;

    float rowsum = 0.0f;
    const int m0 = wave * ROWS_PER_WAVE;
    for (int r0 = 0; r0 < ROWS_PER_WAVE; r0 += RB) {
        float4 x[RB];
        #pragma unroll
        for (int j = 0; j < RB; ++j) x[j] = xS[m0 + r0 + j];  // broadcast b128

        float rmin[RB];
        #pragma unroll
        for (int j = 0; j < RB; ++j) rmin[j] = FINF;

        #pragma unroll
        for (int i = 0; i < CPL; ++i) {
            const float4 yv = yS[i * 64 + lane];   // conflict-free ds_read_b128
            float e[RB];
            #pragma unroll
            for (int j = 0; j < RB; ++j) {
                e[j] = __builtin_fmaf(x[j].x, yv.x,
                        __builtin_fmaf(x[j].y, yv.y,
                         __builtin_fmaf(x[j].z, yv.z, yv.w)));
                rmin[j] = fminf(rmin[j], e[j]);
            }
            float d01 = fminf(e[0] + x[0].w, e[1] + x[1].w);
            float d23 = fminf(e[2] + x[2].w, e[3] + x[3].w);
            colmin[i] = fminf(fminf(colmin[i], d01), d23);
        }

        // 4 interleaved full-wave min reductions (DPP + swizzle + bpermute).
        #pragma unroll
        for (int j = 0; j < RB; ++j) rmin[j] = wave_min64(rmin[j], xaddr32);
        #pragma unroll
        for (int j = 0; j < RB; ++j) rowsum += x[j].w + rmin[j];
    }

    // Publish per-wave partials.
    #pragma unroll
    for (int i = 0; i < CPL; ++i) colminS[wave][i * 64 + lane] = colmin[i];
    if (lane == 0) rowsumS[wave] = rowsum;
    __syncthreads();

    // Cross-wave column-min merge + sum (1 col per thread).
    {
        const int n = tid;
        float cm = colminS[0][n];
        #pragma unroll
        for (int w = 1; w < NWAVES; ++w) cm = fminf(cm, colminS[w][n]);
        float csum = cm;
        #pragma unroll
        for (int off = 32; off > 0; off >>= 1)
            csum += __shfl_xor(csum, off, 64);
        if (lane == 0) csumS[wave] = csum;
    }
    __syncthreads();

    if (tid == 0) {
        float rs = 0.0f, cs = 0.0f;
        #pragma unroll
        for (int w = 0; w < NWAVES; ++w) { rs += rowsumS[w]; cs += csumS[w]; }
        atomicAdd(out, rs * inv_bpm + cs * inv_bpn);
    }
}

extern "C" void kernel_launch(void* const* d_in, const int* in_sizes, int n_in,
                              void* d_out, int out_size, void* d_ws, size_t ws_size,
                              hipStream_t stream) {
    const float* nrf = (const float*)d_in[0];  // (B,P,N,3)
    const float* rp  = (const float*)d_in[1];  // (B,P,M,3)
    float* out = (float*)d_out;

    const int BP = in_sizes[1] / (MM * 3);     // 256
    const float inv_bpm = 1.0f / (float)(BP * MM);
    const float inv_bpn = 1.0f / (float)(BP * NN);

    (void)hipMemsetAsync(out, 0, sizeof(float), stream);
    chamfer_kernel<<<BP, THREADS, 0, stream>>>(nrf, rp, out, inv_bpm, inv_bpn);
}